// Round 4
// baseline (39.029 us; speedup 1.0000x reference)
//
#include <hip/hip_runtime.h>
#include <math.h>

// Problem constants: B=16, N=M=4096, K=64.
#define BB 16
#define NN 4096
#define MM 4096
#define NSLICE 2
#define SLICE_COLS (MM / NSLICE)          // 2048 cols staged per block
#define NROWS_TOTAL (2 * BB * NN)         // 131072

typedef __attribute__((ext_vector_type(8))) short bf16x8;
typedef __attribute__((ext_vector_type(16))) float f32x16;

static __device__ inline unsigned short f2bf(float f) {
    unsigned int u = __float_as_uint(f);
    return (unsigned short)((u + 0x7FFFu + ((u >> 16) & 1u)) >> 16);  // RNE
}
static __device__ inline bf16x8 bzero() {
    bf16x8 z;
    #pragma unroll
    for (int i = 0; i < 8; ++i) z[i] = 0;
    return z;
}
static __device__ inline f32x16 fzero() {
    f32x16 z;
    #pragma unroll
    for (int i = 0; i < 16; ++i) z[i] = 0.f;
    return z;
}

// ---------------------------------------------------------------------------
// Pass A: full d2 via one MFMA: d2 = dot_K5([-2px,-2py,-2pz,p2,1],[tx,ty,tz,1,t2]).
// Wave owns 64 rows (2 A-frags); block stages an M-slice of 2048 packed cols
// in LDS. Lanes>=32 read duplicate B data (their A k-slots are zero). B-frags
// prefetched one jt ahead. Per-slice row-min published via atomicMin on
// order-preserving uint. Grid: (16 row-tiles * NSLICE, B, 2), 4 blocks/CU.
// ---------------------------------------------------------------------------
__global__ __launch_bounds__(256, 4) void chamfer_min_kernel(
    const float* __restrict__ pred, const float* __restrict__ gt,
    unsigned int* __restrict__ wsmin)
{
    __shared__ __align__(16) float smem[8832];  // union: stage 32KB | epilogue 34.5KB

    const int tid  = threadIdx.x;
    const int lane = tid & 63;
    const int w    = tid >> 6;
    const int li   = lane & 31;
    const int hi   = lane >> 5;
    const int tile   = blockIdx.x >> 1;          // 0..15
    const int mslice = blockIdx.x & (NSLICE - 1);
    const int b    = blockIdx.y;
    const int dir  = blockIdx.z;
    const float* rows = dir ? gt : pred;
    const float* cols = dir ? pred : gt;
    const float* rb = rows + (size_t)b * NN * 3;
    const float* cb = cols + ((size_t)b * MM + (size_t)mslice * SLICE_COLS) * 3;

    // A fragments: rows r0..r0+63; lanes 0-31 carry k=0..7 (k=0..4 used),
    // lanes 32-63 carry k=8..15 == 0.
    const int r0 = tile * 256 + w * 64;
    bf16x8 A0 = bzero(), A1 = bzero();
    if (lane < 32) {
        #pragma unroll
        for (int f = 0; f < 2; ++f) {
            const float* rp = rb + (size_t)(r0 + f * 32 + li) * 3;
            const float px = rp[0], py = rp[1], pz = rp[2];
            const float p2 = px * px + py * py + pz * pz;
            bf16x8 fr = bzero();
            fr[0] = (short)f2bf(-2.f * px);
            fr[1] = (short)f2bf(-2.f * py);
            fr[2] = (short)f2bf(-2.f * pz);
            fr[3] = (short)f2bf(p2);
            fr[4] = (short)0x3F80;          // 1.0
            if (f == 0) A0 = fr; else A1 = fr;
        }
    }

    // Stage the slice: packed bf16x8 per col = (tx,ty,tz,1, t2,0,0,0).
    uint4* sB = (uint4*)smem;
    #pragma unroll
    for (int i = 0; i < SLICE_COLS / 256; ++i) {
        const int c = i * 256 + tid;
        const float* tp = cb + (size_t)c * 3;
        const float tx = tp[0], ty = tp[1], tz = tp[2];
        const float t2 = tx * tx + ty * ty + tz * tz;
        uint4 pk;
        pk.x = (unsigned)f2bf(tx) | ((unsigned)f2bf(ty) << 16);  // k0,k1
        pk.y = (unsigned)f2bf(tz) | (0x3F80u << 16);             // k2,k3=1.0
        pk.z = (unsigned)f2bf(t2);                               // k4,k5=0
        pk.w = 0u;
        sB[c] = pk;
    }
    __syncthreads();

    float mv0[16], mv1[16];
    #pragma unroll
    for (int r = 0; r < 16; ++r) { mv0[r] = 3.4e38f; mv1[r] = 3.4e38f; }

    const bf16x8* sBf = (const bf16x8*)smem;

    // Software-pipelined jt loop: prefetch next b-frags, 4 MFMAs, 32 min3.
    bf16x8 b1 = sBf[li], b2 = sBf[32 + li];      // unmasked: lanes>=32 dup, A=0 there
    for (int jt = 0; jt < SLICE_COLS / 64; ++jt) {
        const bf16x8 c1 = b1, c2 = b2;
        if (jt + 1 < SLICE_COLS / 64) {
            b1 = sBf[(jt + 1) * 64 + li];
            b2 = sBf[(jt + 1) * 64 + 32 + li];
        }
        f32x16 a11 = __builtin_amdgcn_mfma_f32_32x32x16_bf16(A0, c1, fzero(), 0, 0, 0);
        f32x16 a12 = __builtin_amdgcn_mfma_f32_32x32x16_bf16(A0, c2, fzero(), 0, 0, 0);
        #pragma unroll
        for (int r = 0; r < 16; ++r)
            mv0[r] = fminf(fminf(a11[r], a12[r]), mv0[r]);   // v_min3_f32
        f32x16 a21 = __builtin_amdgcn_mfma_f32_32x32x16_bf16(A1, c1, fzero(), 0, 0, 0);
        f32x16 a22 = __builtin_amdgcn_mfma_f32_32x32x16_bf16(A1, c2, fzero(), 0, 0, 0);
        #pragma unroll
        for (int r = 0; r < 16; ++r)
            mv1[r] = fminf(fminf(a21[r], a22[r]), mv1[r]);
    }

    // Epilogue: transpose partial mins via LDS (stride 68), reduce 32 col-residues
    // per row, publish via atomicMin (order-preserving uint map).
    __syncthreads();
    {
        float* wb = smem + w * 2208 + li * 68;
        #pragma unroll
        for (int q = 0; q < 4; ++q) {
            const int rl = q * 8 + hi * 4;
            *(float4*)&wb[rl]      = make_float4(mv0[4*q], mv0[4*q+1], mv0[4*q+2], mv0[4*q+3]);
            *(float4*)&wb[rl + 32] = make_float4(mv1[4*q], mv1[4*q+1], mv1[4*q+2], mv1[4*q+3]);
        }
    }
    __syncthreads();

    const float* rbm = smem + w * 2208 + lane;
    float m = 3.4e38f;
    #pragma unroll
    for (int c = 0; c < 32; ++c) m = fminf(m, rbm[c * 68]);

    unsigned int u = __float_as_uint(m);
    u = (u & 0x80000000u) ? ~u : (u | 0x80000000u);
    const int rowg = (dir * BB + b) * NN + r0 + lane;
    atomicMin(&wsmin[rowg], u);
}

// ---------------------------------------------------------------------------
// Pass B: decode per-row min d2, sqrt, mean-reduce, atomicAdd to out.
// ---------------------------------------------------------------------------
__global__ __launch_bounds__(256) void chamfer_finish_kernel(
    const unsigned int* __restrict__ wsmin, float* __restrict__ out)
{
    const int g = blockIdx.x * 256 + threadIdx.x;   // 0 .. 131071
    unsigned int u = wsmin[g];
    const unsigned int bts = (u & 0x80000000u) ? (u & 0x7fffffffu) : ~u;
    float d = sqrtf(fmaxf(__uint_as_float(bts), 0.0f));

    #pragma unroll
    for (int off = 32; off > 0; off >>= 1)
        d += __shfl_down(d, off, 64);
    __shared__ float ssum[4];
    const int tid = threadIdx.x;
    if ((tid & 63) == 0) ssum[tid >> 6] = d;
    __syncthreads();
    if (tid == 0) {
        const float s = ssum[0] + ssum[1] + ssum[2] + ssum[3];
        atomicAdd(out, s * (1.0f / ((float)BB * (float)NN)));
    }
}

// ---------------------------------------------------------------------------
// Regularizer via MFMA: G = T.T^T per batch, one wave per batch (proven R3).
// ---------------------------------------------------------------------------
__global__ __launch_bounds__(64) void reg_kernel(
    const float* __restrict__ trans, float* __restrict__ out)
{
    const int b = blockIdx.x;
    const int lane = threadIdx.x;
    const int hi = lane >> 5, li = lane & 31;
    const float* T = trans + (size_t)b * 64 * 64;

    bf16x8 frag[2][4];
    #pragma unroll
    for (int h = 0; h < 2; ++h) {
        #pragma unroll
        for (int s = 0; s < 4; ++s) {
            const float* rp = T + (size_t)(h * 32 + li) * 64 + s * 16 + hi * 8;
            const float4 u0 = *(const float4*)rp;
            const float4 u1 = *(const float4*)(rp + 4);
            bf16x8 fr;
            fr[0] = (short)f2bf(u0.x); fr[1] = (short)f2bf(u0.y);
            fr[2] = (short)f2bf(u0.z); fr[3] = (short)f2bf(u0.w);
            fr[4] = (short)f2bf(u1.x); fr[5] = (short)f2bf(u1.y);
            fr[6] = (short)f2bf(u1.z); fr[7] = (short)f2bf(u1.w);
            frag[h][s] = fr;
        }
    }

    float fsum = 0.f;
    #pragma unroll
    for (int fi = 0; fi < 2; ++fi) {
        #pragma unroll
        for (int fj = 0; fj < 2; ++fj) {
            f32x16 a = fzero();
            #pragma unroll
            for (int s = 0; s < 4; ++s)
                a = __builtin_amdgcn_mfma_f32_32x32x16_bf16(frag[fi][s], frag[fj][s], a, 0, 0, 0);
            #pragma unroll
            for (int r = 0; r < 16; ++r) {
                const int row = fi * 32 + (r & 3) + 8 * (r >> 2) + 4 * hi;
                const int col = fj * 32 + li;
                const float d = a[r] - ((row == col) ? 1.0f : 0.0f);
                fsum = fmaf(d, d, fsum);
            }
        }
    }

    #pragma unroll
    for (int off = 32; off > 0; off >>= 1)
        fsum += __shfl_down(fsum, off, 64);
    if (lane == 0)
        atomicAdd(out, (0.1f / (float)BB) * sqrtf(fsum));
}

extern "C" void kernel_launch(void* const* d_in, const int* in_sizes, int n_in,
                              void* d_out, int out_size, void* d_ws, size_t ws_size,
                              hipStream_t stream)
{
    const float* pred  = (const float*)d_in[0];
    const float* gt    = (const float*)d_in[1];
    const float* trans = (const float*)d_in[2];
    float* out = (float*)d_out;
    unsigned int* wsmin = (unsigned int*)d_ws;   // 131072 uints = 512 KB

    hipMemsetAsync(out, 0, sizeof(float), stream);
    hipMemsetAsync(wsmin, 0xFF, (size_t)NROWS_TOTAL * sizeof(unsigned int), stream);

    reg_kernel<<<dim3(BB), dim3(64), 0, stream>>>(trans, out);
    chamfer_min_kernel<<<dim3((NN / 256) * NSLICE, BB, 2), dim3(256), 0, stream>>>(
        pred, gt, wsmin);
    chamfer_finish_kernel<<<dim3(NROWS_TOTAL / 256), dim3(256), 0, stream>>>(wsmin, out);
}

// Round 5
// 34.919 us; speedup vs baseline: 1.1177x; 1.1177x over previous
//
#include <hip/hip_runtime.h>
#include <math.h>

// Problem constants: B=16, N=M=4096, K=64.
#define BB 16
#define NN 4096
#define MM 4096
#define NSLICE 2
#define SLICE_COLS (MM / NSLICE)          // 2048 cols staged per block
#define ROWS_PER_WAVE 128                 // 4 A-frags
#define ROWS_PER_BLOCK 512                // 4 waves
#define NROWS_TOTAL (2 * BB * NN)         // 131072
#define EPW 4352                          // epilogue floats per wave (32*136)

typedef __attribute__((ext_vector_type(8))) short bf16x8;
typedef __attribute__((ext_vector_type(16))) float f32x16;

static __device__ inline unsigned short f2bf(float f) {
    unsigned int u = __float_as_uint(f);
    return (unsigned short)((u + 0x7FFFu + ((u >> 16) & 1u)) >> 16);  // RNE
}
static __device__ inline bf16x8 bzero() {
    bf16x8 z;
    #pragma unroll
    for (int i = 0; i < 8; ++i) z[i] = 0;
    return z;
}
static __device__ inline f32x16 fzero() {
    f32x16 z;
    #pragma unroll
    for (int i = 0; i < 16; ++i) z[i] = 0.f;
    return z;
}

// ---------------------------------------------------------------------------
// Pass A: d2 complete in-MFMA: d2 = dot_K5([-2px,-2py,-2pz,p2,1],[tx,ty,tz,1,t2]).
// Wave owns 128 rows (4 A-frags); block stages 2048 packed cols in LDS.
// Per jt: 2 ds_read_b128, 8 independent MFMAs (shared zero-C reg), 64 min3.
// Per-slice row-min written with PLAIN stores (unique writer per (slice,row)).
// Grid: (8 row-tiles * 2 slices, 16, 2) = 512 blocks, 2/CU, 8 waves/CU.
// ---------------------------------------------------------------------------
__global__ __launch_bounds__(256, 2) void chamfer_min_kernel(
    const float* __restrict__ pred, const float* __restrict__ gt,
    float* __restrict__ wsmin)
{
    __shared__ __align__(16) float smem[4 * EPW];   // 69632 B: stage 32KB | epi

    const int tid  = threadIdx.x;
    const int lane = tid & 63;
    const int w    = tid >> 6;
    const int li   = lane & 31;
    const int hi   = lane >> 5;
    const int tile   = blockIdx.x >> 1;             // 0..7
    const int mslice = blockIdx.x & (NSLICE - 1);
    const int b    = blockIdx.y;
    const int dir  = blockIdx.z;
    const float* rows = dir ? gt : pred;
    const float* cols = dir ? pred : gt;
    const float* rb = rows + (size_t)b * NN * 3;
    const float* cb = cols + ((size_t)b * MM + (size_t)mslice * SLICE_COLS) * 3;

    // A fragments: lanes 0-31 carry k=0..7 (k0..4 used); lanes 32-63 zero.
    const int r0 = tile * ROWS_PER_BLOCK + w * ROWS_PER_WAVE;
    bf16x8 A[4];
    #pragma unroll
    for (int f = 0; f < 4; ++f) A[f] = bzero();
    if (lane < 32) {
        #pragma unroll
        for (int f = 0; f < 4; ++f) {
            const float* rp = rb + (size_t)(r0 + f * 32 + li) * 3;
            const float px = rp[0], py = rp[1], pz = rp[2];
            const float p2 = px * px + py * py + pz * pz;
            bf16x8 fr = bzero();
            fr[0] = (short)f2bf(-2.f * px);
            fr[1] = (short)f2bf(-2.f * py);
            fr[2] = (short)f2bf(-2.f * pz);
            fr[3] = (short)f2bf(p2);
            fr[4] = (short)0x3F80;          // 1.0
            A[f] = fr;
        }
    }

    // Stage slice: packed bf16x8 per col = (tx,ty,tz,1, t2,0,0,0).
    uint4* sB = (uint4*)smem;
    #pragma unroll
    for (int i = 0; i < SLICE_COLS / 256; ++i) {
        const int c = i * 256 + tid;
        const float* tp = cb + (size_t)c * 3;
        const float tx = tp[0], ty = tp[1], tz = tp[2];
        const float t2 = tx * tx + ty * ty + tz * tz;
        uint4 pk;
        pk.x = (unsigned)f2bf(tx) | ((unsigned)f2bf(ty) << 16);  // k0,k1
        pk.y = (unsigned)f2bf(tz) | (0x3F80u << 16);             // k2,k3=1.0
        pk.z = (unsigned)f2bf(t2);                               // k4,k5=0
        pk.w = 0u;
        sB[c] = pk;
    }
    __syncthreads();

    float mv[4][16];
    #pragma unroll
    for (int f = 0; f < 4; ++f)
        #pragma unroll
        for (int r = 0; r < 16; ++r) mv[f][r] = 3.4e38f;

    const f32x16 Z = fzero();               // shared zero-C, never overwritten
    const bf16x8* sBf = (const bf16x8*)smem;

    bf16x8 b1 = sBf[li], b2 = sBf[32 + li]; // lanes>=32 dup-read; their A k-slots=0
    for (int jt = 0; jt < SLICE_COLS / 64; ++jt) {
        const bf16x8 c1 = b1, c2 = b2;
        if (jt + 1 < SLICE_COLS / 64) {
            b1 = sBf[(jt + 1) * 64 + li];
            b2 = sBf[(jt + 1) * 64 + 32 + li];
        }
        #pragma unroll
        for (int f = 0; f < 4; ++f) {
            f32x16 a1 = __builtin_amdgcn_mfma_f32_32x32x16_bf16(A[f], c1, Z, 0, 0, 0);
            f32x16 a2 = __builtin_amdgcn_mfma_f32_32x32x16_bf16(A[f], c2, Z, 0, 0, 0);
            #pragma unroll
            for (int r = 0; r < 16; ++r)
                mv[f][r] = fminf(fminf(a1[r], a2[r]), mv[f][r]);   // v_min3_f32
        }
    }

    // Epilogue: transpose partial mins via LDS [col li][row 0..127], stride 136.
    // acc mapping: row_local = f*32 + (r&3) + 8*(r>>2) + 4*hi, col = li.
    __syncthreads();
    {
        float* base = smem + w * EPW + li * 136;
        #pragma unroll
        for (int f = 0; f < 4; ++f)
            #pragma unroll
            for (int q = 0; q < 4; ++q) {
                const int rowl = f * 32 + q * 8 + hi * 4;
                *(float4*)&base[rowl] =
                    make_float4(mv[f][4*q], mv[f][4*q+1], mv[f][4*q+2], mv[f][4*q+3]);
            }
    }
    __syncthreads();

    // One row per thread pair: 512 rows, 256 threads -> rows tid, tid+256.
    #pragma unroll
    for (int half = 0; half < 2; ++half) {
        const int x = half * 256 + tid;             // 0..511
        const int wsrc = x >> 7;
        const int rl = x & 127;
        const float* rb2 = smem + wsrc * EPW + rl;
        float m = 3.4e38f;
        #pragma unroll
        for (int c = 0; c < 32; ++c) m = fminf(m, rb2[c * 136]);
        wsmin[(size_t)mslice * NROWS_TOTAL + (size_t)(dir * BB + b) * NN
              + tile * ROWS_PER_BLOCK + x] = m;
    }
}

// ---------------------------------------------------------------------------
// Pass B (merged): finish chamfer (min over slices, sqrt, mean) + regularizer
// (blocks 0..15, first wave: G = T.T^T via MFMA, ||G-I||_F).
// ---------------------------------------------------------------------------
__global__ __launch_bounds__(256) void finish_reg_kernel(
    const float* __restrict__ wsmin, const float* __restrict__ trans,
    float* __restrict__ out)
{
    const int tid = threadIdx.x;
    const int g = blockIdx.x * 256 + tid;           // 0 .. 131071

    // --- regularizer (no barriers inside) ---
    if (blockIdx.x < BB && tid < 64) {
        const int b = blockIdx.x;
        const int lane = tid;
        const int hi = lane >> 5, li = lane & 31;
        const float* T = trans + (size_t)b * 64 * 64;
        bf16x8 frag[2][4];
        #pragma unroll
        for (int h = 0; h < 2; ++h)
            #pragma unroll
            for (int s = 0; s < 4; ++s) {
                const float* rp = T + (size_t)(h * 32 + li) * 64 + s * 16 + hi * 8;
                const float4 u0 = *(const float4*)rp;
                const float4 u1 = *(const float4*)(rp + 4);
                bf16x8 fr;
                fr[0] = (short)f2bf(u0.x); fr[1] = (short)f2bf(u0.y);
                fr[2] = (short)f2bf(u0.z); fr[3] = (short)f2bf(u0.w);
                fr[4] = (short)f2bf(u1.x); fr[5] = (short)f2bf(u1.y);
                fr[6] = (short)f2bf(u1.z); fr[7] = (short)f2bf(u1.w);
                frag[h][s] = fr;
            }
        float fsum = 0.f;
        #pragma unroll
        for (int fi = 0; fi < 2; ++fi)
            #pragma unroll
            for (int fj = 0; fj < 2; ++fj) {
                f32x16 a = fzero();
                #pragma unroll
                for (int s = 0; s < 4; ++s)
                    a = __builtin_amdgcn_mfma_f32_32x32x16_bf16(frag[fi][s], frag[fj][s], a, 0, 0, 0);
                #pragma unroll
                for (int r = 0; r < 16; ++r) {
                    const int row = fi * 32 + (r & 3) + 8 * (r >> 2) + 4 * hi;
                    const int col = fj * 32 + li;
                    const float d = a[r] - ((row == col) ? 1.0f : 0.0f);
                    fsum = fmaf(d, d, fsum);
                }
            }
        #pragma unroll
        for (int off = 32; off > 0; off >>= 1)
            fsum += __shfl_down(fsum, off, 64);
        if (lane == 0)
            atomicAdd(out, (0.1f / (float)BB) * sqrtf(fsum));
    }

    // --- chamfer finish ---
    const float v = fminf(wsmin[g], wsmin[NROWS_TOTAL + g]);
    float d = sqrtf(fmaxf(v, 0.0f));
    #pragma unroll
    for (int off = 32; off > 0; off >>= 1)
        d += __shfl_down(d, off, 64);
    __shared__ float ssum[4];
    if ((tid & 63) == 0) ssum[tid >> 6] = d;
    __syncthreads();
    if (tid == 0) {
        const float s = ssum[0] + ssum[1] + ssum[2] + ssum[3];
        atomicAdd(out, s * (1.0f / ((float)BB * (float)NN)));
    }
}

extern "C" void kernel_launch(void* const* d_in, const int* in_sizes, int n_in,
                              void* d_out, int out_size, void* d_ws, size_t ws_size,
                              hipStream_t stream)
{
    const float* pred  = (const float*)d_in[0];
    const float* gt    = (const float*)d_in[1];
    const float* trans = (const float*)d_in[2];
    float* out = (float*)d_out;
    float* wsmin = (float*)d_ws;   // NSLICE * 131072 floats = 1 MB, plain stores

    hipMemsetAsync(out, 0, sizeof(float), stream);

    chamfer_min_kernel<<<dim3((NN / ROWS_PER_BLOCK) * NSLICE, BB, 2),
                         dim3(256), 0, stream>>>(pred, gt, wsmin);
    finish_reg_kernel<<<dim3(NROWS_TOTAL / 256), dim3(256), 0, stream>>>(
        wsmin, trans, out);
}